// Round 4
// baseline (129.522 us; speedup 1.0000x reference)
//
#include <hip/hip_runtime.h>
#include <hip/hip_bf16.h>
#include <math.h>

// Problem constants
#define K_  32
#define HN  16      // n/2
#define N_  32
#define M_  128
#define B_  8
#define T_  2048
#define D_  128
#define BT  (B_*T_)     // 16384
#define KA  1056        // GEMM K: 1024 interleaved (Re,Im) + 32 xp
#define CHK 32          // chunks per series (k_seed pass-1)
#define CL  64          // chunk length (T/CHK)
#define ABYTES 2176     // LDS A-tile row stride in bytes (17*128, XOR-swizzle friendly)

typedef short short8 __attribute__((ext_vector_type(8)));
typedef float floatx4 __attribute__((ext_vector_type(4)));
typedef unsigned short ushort_t;
typedef unsigned int uint_t;

__device__ __forceinline__ ushort_t f2bf(float f) {
    __hip_bfloat16 h = __float2bfloat16(f);
    return *reinterpret_cast<ushort_t*>(&h);
}
__device__ __forceinline__ uint_t pack_bf2(float re, float im) {
    return ((uint_t)f2bf(im) << 16) | (uint_t)f2bf(re);
}

// ---------------------------------------------------------------------------
// K_PRE: verified round-0/3 version, unchanged (writes ws, Wt, xpT, A2 D-cols).
// ---------------------------------------------------------------------------
__global__ __launch_bounds__(256) void k_pre(const float* __restrict__ theta,
                                             const float* __restrict__ lnC_r,
                                             const float* __restrict__ lnC_i,
                                             const float* __restrict__ D,
                                             const float* __restrict__ x,
                                             const float* __restrict__ R,
                                             float* __restrict__ ws,
                                             ushort_t* __restrict__ Wt,
                                             float* __restrict__ xpT,
                                             ushort_t* __restrict__ A2) {
    __shared__ float xls[32 * 128];
    int bid = blockIdx.x, tid = threadIdx.x;
    if (bid == 0) {
        // ---- lambda & Bp ----
        #pragma unroll
        for (int rep = 0; rep < 2; ++rep) {
            int t2 = rep * 256 + tid;          // k*16 + j
            int k = t2 >> 4, j = t2 & 15;
            float angj = theta[k * HN + j];
            float pr = 1.f, pi = 0.f;
            for (int i = 0; i < N_; ++i) {
                if (i == j) continue;
                float angi = (i < HN) ? theta[k * HN + i] : -theta[k * HN + i - HN];
                float d = angi - angj;
                float tr = 1.f - cosf(d);
                float ti = -sinf(d);
                float nr = pr * tr - pi * ti;
                float ni = pr * ti + pi * tr;
                pr = nr; pi = ni;
            }
            float den = pr * pr + pi * pi;
            ws[t2]        = cosf(angj);
            ws[512 + t2]  = sinf(angj);
            ws[1024 + t2] = pr / den;
            ws[1536 + t2] = -pi / den;
        }
    } else if (bid <= 272) {
        // ---- Wt build ----
        int t = (bid - 1) * 256 + tid;
        const float inv = 1.f / 32.f;
        if (t < K_ * HN * M_) {                 // 65536
            int m = t & 127, j = (t >> 7) & 15, k = t >> 11;
            int i0 = (k * N_ + j) * M_ + m;
            int i1 = (k * N_ + j + HN) * M_ + m;
            float r0 = expf(lnC_r[i0]), c0 = cosf(lnC_i[i0]), s0 = sinf(lnC_i[i0]);
            float r1 = expf(lnC_r[i1]), c1 = cosf(lnC_i[i1]), s1 = sinf(lnC_i[i1]);
            float wr = (r0 * c0 + r1 * c1) * inv;
            float wi = (r1 * s1 - r0 * s0) * inv;
            *(uint_t*)(Wt + (size_t)m * KA + k * 32 + 2 * j) = pack_bf2(wr, wi);
        } else if (t < K_ * HN * M_ + K_ * M_) {
            int u = t - K_ * HN * M_;
            int m = u & 127, k = u >> 7;
            Wt[(size_t)m * KA + 1024 + k] = f2bf(D[k * M_ + m] * inv);
        }
    } else {
        // ---- xp projection ----
        int xb = bid - 273;                     // 0..511
        int b = xb >> 6;
        int tbase = (xb & 63) * 32;
        const float4* xsrc = (const float4*)(x + ((size_t)b * T_ + tbase) * D_);
        float4* xd = (float4*)xls;
        #pragma unroll
        for (int e = 0; e < 4; ++e) xd[tid + 256 * e] = xsrc[tid + 256 * e];
        __syncthreads();
        int kk = tid & 31, rg = tid >> 5;       // rg 0..7
        float accv[4] = {0.f, 0.f, 0.f, 0.f};
        #pragma unroll 4
        for (int i = 0; i < D_; ++i) {
            float rv = R[i * K_ + kk];
            #pragma unroll
            for (int rr = 0; rr < 4; ++rr)
                accv[rr] += xls[(rg + 8 * rr) * D_ + i] * rv;
        }
        #pragma unroll
        for (int rr = 0; rr < 4; ++rr) {
            int tt = tbase + rg + 8 * rr;
            A2[(size_t)(tt * 8 + b) * KA + 1024 + kk] = f2bf(accv[rr]);
            size_t base = (size_t)(b * K_ + kk) * T_;
            if (tt < T_ - 1) xpT[base + tt + 1] = accv[rr];
            if (tt == 0)     xpT[base] = 0.f;
        }
    }
}

// ---------------------------------------------------------------------------
// K_SEED (bisection C): verified k_scan pass-1 + carry combine (identical
// text), then pass-2-lite: store the state seeds at 32-step boundaries.
//   seeds[(b*64 + c32)*512 + k*16+j] = s_{c32*32 - 1}
// Each stored seed is an intermediate state of the verified chain
// (bit-identical by construction).
// ---------------------------------------------------------------------------
__global__ __launch_bounds__(512) void k_seed(const float* __restrict__ xpT,
                                              const float* __restrict__ ws,
                                              float2* __restrict__ seeds) {
    __shared__ float xls[T_];          // 8 KB
    __shared__ float Er[512], Ei[512]; // 4 KB

    int tid = threadIdx.x;
    int k = blockIdx.x & 31, b = blockIdx.x >> 5;
    int c = tid >> 4, j = tid & 15;
    int col = k * 16 + j;

    // stage series
    ((float4*)xls)[tid] = ((const float4*)(xpT + (size_t)(b * K_ + k) * T_))[tid];
    __syncthreads();

    float lr = ws[col], li = ws[512 + col];
    float br = ws[1024 + col], bi = ws[1536 + col];

    // pass-1: chunk end-state (verified text)
    {
        float sr = 0.f, si = 0.f;
        const float* xc = xls + c * CL;
        #pragma unroll 4
        for (int p = 0; p < CL; ++p) {
            float x1 = xc[p];
            float nr = br * x1 + lr * sr - li * si;
            float ni = bi * x1 + lr * si + li * sr;
            sr = nr; si = ni;
        }
        Er[c * 16 + j] = sr;
        Ei[c * 16 + j] = si;
    }
    __syncthreads();

    // carry combine (verified text): E[c] becomes the SEED of chunk c
    if (tid < 16) {
        float pr = lr, pi = li;            // lambda^64 via 6 squarings
        #pragma unroll
        for (int q = 0; q < 6; ++q) {
            float nr = pr * pr - pi * pi;
            float ni = 2.f * pr * pi;
            pr = nr; pi = ni;
        }
        float sr = 0.f, si = 0.f;
        for (int cc = 0; cc < CHK; ++cc) {
            int idx = cc * 16 + tid;
            float er = Er[idx], ei = Ei[idx];
            Er[idx] = sr; Ei[idx] = si;
            float nr = pr * sr - pi * si + er;
            float ni = pr * si + pi * sr + ei;
            sr = nr; si = ni;
        }
    }
    __syncthreads();

    // pass-2-lite: store seed of chunk 2c, replay 32 steps, store seed 2c+1
    {
        float sr = Er[c * 16 + j], si = Ei[c * 16 + j];
        size_t sb = ((size_t)(b * 64 + 2 * c) * 512) + col;
        seeds[sb] = make_float2(sr, si);
        const float* xc = xls + c * CL;
        #pragma unroll 4
        for (int p = 0; p < 32; ++p) {
            float x1 = xc[p];
            float nr = br * x1 + lr * sr - li * si;
            float ni = bi * x1 + lr * si + li * sr;
            sr = nr; si = ni;
        }
        seeds[sb + 512] = make_float2(sr, si);
    }
}

// ---------------------------------------------------------------------------
// K_EXPAND (bisection C): seed-replay -> verified A2 layout, coalesced.
// 512 blocks x 512 threads; block (b = bid>>6, c32 = bid&63), t0 = c32*32.
// Thread tid = series col (k = tid>>4, j = tid&15). Replays 32 steps with
// the same f32 ops on the same xpT values as the verified chain, writes
// pack_bf2 to A2 rows r=(t0+p)*8+b — per-p the 512 threads write uints
// 0..511 of one row (fully coalesced). D-cols (512..527) untouched (k_pre).
// ---------------------------------------------------------------------------
__global__ __launch_bounds__(512) void k_expand(const float* __restrict__ xpT,
                                                const float* __restrict__ ws,
                                                const float2* __restrict__ seeds,
                                                uint_t* __restrict__ A2u) {
    __shared__ float xs[32 * 33];   // [k][p], +1 pad
    int tid = threadIdx.x;
    int b = blockIdx.x >> 6, c32 = blockIdx.x & 63;
    int t0 = c32 * 32;
    int k = tid >> 4, j = tid & 15;

    {
        const float* src = xpT + (size_t)(b * K_ + k) * T_ + t0;
        for (int p = j; p < 32; p += 16) xs[k * 33 + p] = src[p];
    }
    float lr = ws[tid], li = ws[512 + tid];
    float br = ws[1024 + tid], bi = ws[1536 + tid];
    float2 sd = seeds[((size_t)(b * 64 + c32) * 512) + tid];
    __syncthreads();

    float sr = sd.x, si = sd.y;
    uint_t* Ab = A2u + (size_t)(t0 * 8 + b) * (KA / 2) + tid;
    #pragma unroll 4
    for (int p = 0; p < 32; ++p) {
        float x1 = xs[k * 33 + p];
        float nr = br * x1 + lr * sr - li * si;
        float ni = bi * x1 + lr * si + li * sr;
        sr = nr; si = ni;
        Ab[0] = pack_bf2(sr, si);
        Ab += 8 * (KA / 2);
    }
}

// ---------------------------------------------------------------------------
// K_GEMM2: verified round-3 version, unchanged.
// ---------------------------------------------------------------------------
__global__ __launch_bounds__(512) void k_gemm2(const uint_t* __restrict__ A2u,
                                               const ushort_t* __restrict__ Wt,
                                               const float* __restrict__ Do,
                                               float* __restrict__ out) {
    __shared__ __align__(16) char smem[32 * ABYTES];   // 69632 B

    int tid = threadIdx.x;
    int bid = blockIdx.x;

    // stage: 16896 uints = 32 rows x 528, flat, coalesced
    const uint_t* src = A2u + (size_t)bid * (32 * (KA / 2));
    for (int it = 0; it < 33; ++it) {
        int f = it * 512 + tid;
        int row = f / 528;
        int uc = f - row * 528;
        int bo = (row * ABYTES + uc * 4) ^ ((row & 7) << 4);
        *(uint_t*)(smem + bo) = src[f];
    }
    __syncthreads();

    int wave = tid >> 6, lane = tid & 63;
    int l16 = lane & 15, quad = lane >> 4;
    int rh = wave & 1, cf = wave >> 1;
    int arow = rh * 16 + l16;
    int abase = arow * ABYTES + quad * 16;
    int aswz = (arow & 7) << 4;
    const ushort_t* Wp0 = Wt + (size_t)(cf * 32 + l16) * KA + quad * 8;
    const ushort_t* Wp1 = Wp0 + (size_t)16 * KA;

    floatx4 acc0 = {0.f, 0.f, 0.f, 0.f}, acc1 = {0.f, 0.f, 0.f, 0.f};
    for (int ks = 0; ks < 33; ++ks) {
        short8 av = *(const short8*)(smem + ((abase + ks * 64) ^ aswz));
        short8 b0 = *(const short8*)(Wp0 + ks * 32);
        short8 b1 = *(const short8*)(Wp1 + ks * 32);
        acc0 = __builtin_amdgcn_mfma_f32_16x16x32_bf16(av, b0, acc0, 0, 0, 0);
        acc1 = __builtin_amdgcn_mfma_f32_16x16x32_bf16(av, b1, acc1, 0, 0, 0);
    }

    int col0 = cf * 32 + l16;
    float dv0 = Do[col0], dv1 = Do[col0 + 16];
    #pragma unroll
    for (int q = 0; q < 4; ++q) {
        int r = bid * 32 + rh * 16 + quad * 4 + q;
        int b = r & 7, t = r >> 3;
        float* op = out + (size_t)(b * T_ + t) * M_;
        op[col0]      = acc0[q] + dv0;
        op[col0 + 16] = acc1[q] + dv1;
    }
}

// ---------------------------------------------------------------------------
extern "C" void kernel_launch(void* const* d_in, const int* in_sizes, int n_in,
                              void* d_out, int out_size, void* d_ws, size_t ws_size,
                              hipStream_t stream) {
    const float* x     = (const float*)d_in[0];
    const float* R     = (const float*)d_in[1];
    const float* theta = (const float*)d_in[2];
    const float* lnC_r = (const float*)d_in[3];
    const float* lnC_i = (const float*)d_in[4];
    const float* D     = (const float*)d_in[5];
    const float* Do    = (const float*)d_in[6];
    float* out = (float*)d_out;

    float* wsf    = (float*)d_ws;
    float* lambp  = wsf;                               // 2048 floats
    ushort_t* Wt  = (ushort_t*)(wsf + 2048);           // 135168 ushorts = 67584 floats
    ushort_t* A2  = (ushort_t*)(wsf + 2048 + 67584);   // BT*KA ushorts = 8650752 floats
    float* xpT    = wsf + 2048 + 67584 + 8650752;      // 524288 floats
    float2* seeds = (float2*)(wsf + 2048 + 67584 + 8650752 + 524288); // 262144 float2

    k_pre<<<785, 256, 0, stream>>>(theta, lnC_r, lnC_i, D, x, R,
                                   lambp, Wt, xpT, A2);
    k_seed<<<256, 512, 0, stream>>>(xpT, lambp, seeds);
    k_expand<<<512, 512, 0, stream>>>(xpT, lambp, seeds, (uint_t*)A2);
    k_gemm2<<<512, 512, 0, stream>>>((const uint_t*)A2, Wt, Do, out);
}

// Round 8
// 126.841 us; speedup vs baseline: 1.0211x; 1.0211x over previous
//
#include <hip/hip_runtime.h>
#include <hip/hip_bf16.h>
#include <math.h>

// Problem constants
#define K_  32
#define HN  16      // n/2
#define N_  32
#define M_  128
#define B_  8
#define T_  2048
#define D_  128
#define BT  (B_*T_)     // 16384
#define KA  1056        // GEMM K: 1024 interleaved (Re,Im) + 32 xp
#define CHK 32          // chunks per series
#define CL  64          // chunk length (T/CHK)
#define ABYTES 2176     // LDS A-tile row stride in bytes (17*128, XOR-swizzle friendly)

typedef short short8 __attribute__((ext_vector_type(8)));
typedef float floatx4 __attribute__((ext_vector_type(4)));
typedef unsigned short ushort_t;
typedef unsigned int uint_t;

__device__ __forceinline__ ushort_t f2bf(float f) {
    __hip_bfloat16 h = __float2bfloat16(f);
    return *reinterpret_cast<ushort_t*>(&h);
}
__device__ __forceinline__ uint_t pack_bf2(float re, float im) {
    return ((uint_t)f2bf(im) << 16) | (uint_t)f2bf(re);
}

// ---------------------------------------------------------------------------
// K_PRE: verified round-0/3 version, unchanged.
// ---------------------------------------------------------------------------
__global__ __launch_bounds__(256) void k_pre(const float* __restrict__ theta,
                                             const float* __restrict__ lnC_r,
                                             const float* __restrict__ lnC_i,
                                             const float* __restrict__ D,
                                             const float* __restrict__ x,
                                             const float* __restrict__ R,
                                             float* __restrict__ ws,
                                             ushort_t* __restrict__ Wt,
                                             float* __restrict__ xpT,
                                             ushort_t* __restrict__ A2) {
    __shared__ float xls[32 * 128];
    int bid = blockIdx.x, tid = threadIdx.x;
    if (bid == 0) {
        // ---- lambda & Bp ----
        #pragma unroll
        for (int rep = 0; rep < 2; ++rep) {
            int t2 = rep * 256 + tid;          // k*16 + j
            int k = t2 >> 4, j = t2 & 15;
            float angj = theta[k * HN + j];
            float pr = 1.f, pi = 0.f;
            for (int i = 0; i < N_; ++i) {
                if (i == j) continue;
                float angi = (i < HN) ? theta[k * HN + i] : -theta[k * HN + i - HN];
                float d = angi - angj;
                float tr = 1.f - cosf(d);
                float ti = -sinf(d);
                float nr = pr * tr - pi * ti;
                float ni = pr * ti + pi * tr;
                pr = nr; pi = ni;
            }
            float den = pr * pr + pi * pi;
            ws[t2]        = cosf(angj);
            ws[512 + t2]  = sinf(angj);
            ws[1024 + t2] = pr / den;
            ws[1536 + t2] = -pi / den;
        }
    } else if (bid <= 272) {
        // ---- Wt build ----
        int t = (bid - 1) * 256 + tid;
        const float inv = 1.f / 32.f;
        if (t < K_ * HN * M_) {                 // 65536
            int m = t & 127, j = (t >> 7) & 15, k = t >> 11;
            int i0 = (k * N_ + j) * M_ + m;
            int i1 = (k * N_ + j + HN) * M_ + m;
            float r0 = expf(lnC_r[i0]), c0 = cosf(lnC_i[i0]), s0 = sinf(lnC_i[i0]);
            float r1 = expf(lnC_r[i1]), c1 = cosf(lnC_i[i1]), s1 = sinf(lnC_i[i1]);
            float wr = (r0 * c0 + r1 * c1) * inv;
            float wi = (r1 * s1 - r0 * s0) * inv;
            *(uint_t*)(Wt + (size_t)m * KA + k * 32 + 2 * j) = pack_bf2(wr, wi);
        } else if (t < K_ * HN * M_ + K_ * M_) {
            int u = t - K_ * HN * M_;
            int m = u & 127, k = u >> 7;
            Wt[(size_t)m * KA + 1024 + k] = f2bf(D[k * M_ + m] * inv);
        }
    } else {
        // ---- xp projection ----
        int xb = bid - 273;                     // 0..511
        int b = xb >> 6;
        int tbase = (xb & 63) * 32;
        const float4* xsrc = (const float4*)(x + ((size_t)b * T_ + tbase) * D_);
        float4* xd = (float4*)xls;
        #pragma unroll
        for (int e = 0; e < 4; ++e) xd[tid + 256 * e] = xsrc[tid + 256 * e];
        __syncthreads();
        int kk = tid & 31, rg = tid >> 5;       // rg 0..7
        float accv[4] = {0.f, 0.f, 0.f, 0.f};
        #pragma unroll 4
        for (int i = 0; i < D_; ++i) {
            float rv = R[i * K_ + kk];
            #pragma unroll
            for (int rr = 0; rr < 4; ++rr)
                accv[rr] += xls[(rg + 8 * rr) * D_ + i] * rv;
        }
        #pragma unroll
        for (int rr = 0; rr < 4; ++rr) {
            int tt = tbase + rg + 8 * rr;
            A2[(size_t)(tt * 8 + b) * KA + 1024 + kk] = f2bf(accv[rr]);
            size_t base = (size_t)(b * K_ + kk) * T_;
            if (tt < T_ - 1) xpT[base + tt + 1] = accv[rr];
            if (tt == 0)     xpT[base] = 0.f;
        }
    }
}

// ---------------------------------------------------------------------------
// K_SCAN: verified round-0/3 version, unchanged. Writes full bf16 A2 states.
// ---------------------------------------------------------------------------
__global__ __launch_bounds__(512) void k_scan(const float* __restrict__ xpT,
                                              const float* __restrict__ ws,
                                              uint_t* __restrict__ A2u) {
    __shared__ float xls[T_];          // 8 KB
    __shared__ float Er[512], Ei[512]; // 4 KB  (E, then seeds, [c*16+j])

    int tid = threadIdx.x;
    int k = blockIdx.x & 31, b = blockIdx.x >> 5;
    int c = tid >> 4, j = tid & 15;
    int col = k * 16 + j;

    // 1) stage series
    ((float4*)xls)[tid] = ((const float4*)(xpT + (size_t)(b * K_ + k) * T_))[tid];
    __syncthreads();

    float lr = ws[col], li = ws[512 + col];
    float br = ws[1024 + col], bi = ws[1536 + col];

    // 2) pass-1: chunk end-state
    {
        float sr = 0.f, si = 0.f;
        const float* xc = xls + c * CL;
        #pragma unroll 4
        for (int p = 0; p < CL; ++p) {
            float x1 = xc[p];
            float nr = br * x1 + lr * sr - li * si;
            float ni = bi * x1 + lr * si + li * sr;
            sr = nr; si = ni;
        }
        Er[c * 16 + j] = sr;
        Ei[c * 16 + j] = si;
    }
    __syncthreads();

    // 3) carry combine (16 threads), in-place: E[c] becomes the SEED of chunk c
    if (tid < 16) {
        float pr = lr, pi = li;            // lambda^64 via 6 squarings
        #pragma unroll
        for (int q = 0; q < 6; ++q) {
            float nr = pr * pr - pi * pi;
            float ni = 2.f * pr * pi;
            pr = nr; pi = ni;
        }
        float sr = 0.f, si = 0.f;
        for (int cc = 0; cc < CHK; ++cc) {
            int idx = cc * 16 + tid;
            float er = Er[idx], ei = Ei[idx];
            Er[idx] = sr; Ei[idx] = si;
            float nr = pr * sr - pi * si + er;
            float ni = pr * si + pi * sr + ei;
            sr = nr; si = ni;
        }
    }
    __syncthreads();

    // 4) pass-2: seeded scan, write A2
    {
        float sr = Er[c * 16 + j], si = Ei[c * 16 + j];
        int t0 = c * CL;
        const float* xc = xls + t0;
        uint_t* Ab = A2u + (size_t)(t0 * 8 + b) * (KA / 2) + col;
        #pragma unroll 4
        for (int p = 0; p < CL; ++p) {
            float x1 = xc[p];
            float nr = br * x1 + lr * sr - li * si;
            float ni = bi * x1 + lr * si + li * sr;
            sr = nr; si = ni;
            Ab[0] = pack_bf2(sr, si);
            Ab += 8 * (KA / 2);
        }
    }
}

// ---------------------------------------------------------------------------
// K_GEMM2: verified round-3 kernel with ONE change — the stage loop is
// vectorized from 33x4B to 9x16B per thread. The XOR swizzle only touches
// byte-address bits 4..6, so every 16B-aligned chunk maps to a contiguous
// 16B LDS destination: for uints u in chunk c16 (u = c16*4..c16*4+3),
//   (row*ABYTES + u*4) ^ swz == ((row*ABYTES + c16*16) ^ swz) + (u&3)*4.
// Same cells, same values -> LDS content bit-identical to round 3 ->
// MFMA inputs and output bit-identical.
// ---------------------------------------------------------------------------
__global__ __launch_bounds__(512) void k_gemm2(const uint_t* __restrict__ A2u,
                                               const ushort_t* __restrict__ Wt,
                                               const float* __restrict__ Do,
                                               float* __restrict__ out) {
    __shared__ __align__(16) char smem[32 * ABYTES];   // 69632 B

    int tid = threadIdx.x;
    int bid = blockIdx.x;

    // stage: 4224 x 16B chunks = 32 rows x 132 chunks, flat, coalesced
    const uint4* src4 = (const uint4*)(A2u + (size_t)bid * (32 * (KA / 2)));
    #pragma unroll
    for (int it = 0; it < 9; ++it) {
        int f = it * 512 + tid;
        if (f < 4224) {
            uint4 v = src4[f];
            int row = f / 132;
            int c16 = f - row * 132;
            int bo = (row * ABYTES + c16 * 16) ^ ((row & 7) << 4);
            *(uint4*)(smem + bo) = v;
        }
    }
    __syncthreads();

    int wave = tid >> 6, lane = tid & 63;
    int l16 = lane & 15, quad = lane >> 4;
    int rh = wave & 1, cf = wave >> 1;
    int arow = rh * 16 + l16;
    int abase = arow * ABYTES + quad * 16;
    int aswz = (arow & 7) << 4;
    const ushort_t* Wp0 = Wt + (size_t)(cf * 32 + l16) * KA + quad * 8;
    const ushort_t* Wp1 = Wp0 + (size_t)16 * KA;

    floatx4 acc0 = {0.f, 0.f, 0.f, 0.f}, acc1 = {0.f, 0.f, 0.f, 0.f};
    for (int ks = 0; ks < 33; ++ks) {
        short8 av = *(const short8*)(smem + ((abase + ks * 64) ^ aswz));
        short8 b0 = *(const short8*)(Wp0 + ks * 32);
        short8 b1 = *(const short8*)(Wp1 + ks * 32);
        acc0 = __builtin_amdgcn_mfma_f32_16x16x32_bf16(av, b0, acc0, 0, 0, 0);
        acc1 = __builtin_amdgcn_mfma_f32_16x16x32_bf16(av, b1, acc1, 0, 0, 0);
    }

    int col0 = cf * 32 + l16;
    float dv0 = Do[col0], dv1 = Do[col0 + 16];
    #pragma unroll
    for (int q = 0; q < 4; ++q) {
        int r = bid * 32 + rh * 16 + quad * 4 + q;
        int b = r & 7, t = r >> 3;
        float* op = out + (size_t)(b * T_ + t) * M_;
        op[col0]      = acc0[q] + dv0;
        op[col0 + 16] = acc1[q] + dv1;
    }
}

// ---------------------------------------------------------------------------
extern "C" void kernel_launch(void* const* d_in, const int* in_sizes, int n_in,
                              void* d_out, int out_size, void* d_ws, size_t ws_size,
                              hipStream_t stream) {
    const float* x     = (const float*)d_in[0];
    const float* R     = (const float*)d_in[1];
    const float* theta = (const float*)d_in[2];
    const float* lnC_r = (const float*)d_in[3];
    const float* lnC_i = (const float*)d_in[4];
    const float* D     = (const float*)d_in[5];
    const float* Do    = (const float*)d_in[6];
    float* out = (float*)d_out;

    float* wsf   = (float*)d_ws;
    float* lambp = wsf;                               // 2048 floats
    ushort_t* Wt = (ushort_t*)(wsf + 2048);           // 135168 ushorts = 67584 floats
    ushort_t* A2 = (ushort_t*)(wsf + 2048 + 67584);   // BT*KA ushorts = 8650752 floats
    float* xpT   = wsf + 2048 + 67584 + 8650752;      // 524288 floats

    k_pre<<<785, 256, 0, stream>>>(theta, lnC_r, lnC_i, D, x, R,
                                   lambp, Wt, xpT, A2);
    k_scan<<<256, 512, 0, stream>>>(xpT, lambp, (uint_t*)A2);
    k_gemm2<<<512, 512, 0, stream>>>((const uint_t*)A2, Wt, Do, out);
}

// Round 9
// 125.380 us; speedup vs baseline: 1.0330x; 1.0117x over previous
//
#include <hip/hip_runtime.h>
#include <hip/hip_bf16.h>
#include <math.h>

// Problem constants
#define K_  32
#define HN  16      // n/2
#define N_  32
#define M_  128
#define B_  8
#define T_  2048
#define D_  128
#define BT  (B_*T_)     // 16384
#define KA  1056        // GEMM K: 1024 interleaved (Re,Im) + 32 xp
#define CHK 32          // chunks per series
#define CL  64          // chunk length (T/CHK)
#define ABYTES 2176     // LDS A-tile row stride in bytes (17*128, XOR-swizzle friendly)

typedef short short8 __attribute__((ext_vector_type(8)));
typedef float floatx4 __attribute__((ext_vector_type(4)));
typedef unsigned short ushort_t;
typedef unsigned int uint_t;

__device__ __forceinline__ ushort_t f2bf(float f) {
    __hip_bfloat16 h = __float2bfloat16(f);
    return *reinterpret_cast<ushort_t*>(&h);
}
__device__ __forceinline__ uint_t pack_bf2(float re, float im) {
    return ((uint_t)f2bf(im) << 16) | (uint_t)f2bf(re);
}

// ---------------------------------------------------------------------------
// K_PRE: round-8 version with ONE change: the xp-projection inner loop reads
// xls via float4 (ds_read_b128, 128 reads/thread instead of 512 ds_read_b32)
// and accumulates the 4 elements in ascending-i order with the same `+=`
// statements -> identical FMA contraction sequence -> bit-identical accv.
// ---------------------------------------------------------------------------
__global__ __launch_bounds__(256) void k_pre(const float* __restrict__ theta,
                                             const float* __restrict__ lnC_r,
                                             const float* __restrict__ lnC_i,
                                             const float* __restrict__ D,
                                             const float* __restrict__ x,
                                             const float* __restrict__ R,
                                             float* __restrict__ ws,
                                             ushort_t* __restrict__ Wt,
                                             float* __restrict__ xpT,
                                             ushort_t* __restrict__ A2) {
    __shared__ float xls[32 * 128];
    int bid = blockIdx.x, tid = threadIdx.x;
    if (bid == 0) {
        // ---- lambda & Bp ----
        #pragma unroll
        for (int rep = 0; rep < 2; ++rep) {
            int t2 = rep * 256 + tid;          // k*16 + j
            int k = t2 >> 4, j = t2 & 15;
            float angj = theta[k * HN + j];
            float pr = 1.f, pi = 0.f;
            for (int i = 0; i < N_; ++i) {
                if (i == j) continue;
                float angi = (i < HN) ? theta[k * HN + i] : -theta[k * HN + i - HN];
                float d = angi - angj;
                float tr = 1.f - cosf(d);
                float ti = -sinf(d);
                float nr = pr * tr - pi * ti;
                float ni = pr * ti + pi * tr;
                pr = nr; pi = ni;
            }
            float den = pr * pr + pi * pi;
            ws[t2]        = cosf(angj);
            ws[512 + t2]  = sinf(angj);
            ws[1024 + t2] = pr / den;
            ws[1536 + t2] = -pi / den;
        }
    } else if (bid <= 272) {
        // ---- Wt build ----
        int t = (bid - 1) * 256 + tid;
        const float inv = 1.f / 32.f;
        if (t < K_ * HN * M_) {                 // 65536
            int m = t & 127, j = (t >> 7) & 15, k = t >> 11;
            int i0 = (k * N_ + j) * M_ + m;
            int i1 = (k * N_ + j + HN) * M_ + m;
            float r0 = expf(lnC_r[i0]), c0 = cosf(lnC_i[i0]), s0 = sinf(lnC_i[i0]);
            float r1 = expf(lnC_r[i1]), c1 = cosf(lnC_i[i1]), s1 = sinf(lnC_i[i1]);
            float wr = (r0 * c0 + r1 * c1) * inv;
            float wi = (r1 * s1 - r0 * s0) * inv;
            *(uint_t*)(Wt + (size_t)m * KA + k * 32 + 2 * j) = pack_bf2(wr, wi);
        } else if (t < K_ * HN * M_ + K_ * M_) {
            int u = t - K_ * HN * M_;
            int m = u & 127, k = u >> 7;
            Wt[(size_t)m * KA + 1024 + k] = f2bf(D[k * M_ + m] * inv);
        }
    } else {
        // ---- xp projection (float4 LDS reads; ascending-i accumulate) ----
        int xb = bid - 273;                     // 0..511
        int b = xb >> 6;
        int tbase = (xb & 63) * 32;
        const float4* xsrc = (const float4*)(x + ((size_t)b * T_ + tbase) * D_);
        float4* xd = (float4*)xls;
        #pragma unroll
        for (int e = 0; e < 4; ++e) xd[tid + 256 * e] = xsrc[tid + 256 * e];
        __syncthreads();
        int kk = tid & 31, rg = tid >> 5;       // rg 0..7
        float accv[4] = {0.f, 0.f, 0.f, 0.f};
        #pragma unroll 2
        for (int i4 = 0; i4 < 32; ++i4) {
            int i = i4 * 4;
            float r0 = R[(i + 0) * K_ + kk];
            float r1 = R[(i + 1) * K_ + kk];
            float r2 = R[(i + 2) * K_ + kk];
            float r3 = R[(i + 3) * K_ + kk];
            #pragma unroll
            for (int rr = 0; rr < 4; ++rr) {
                float4 xv = *(const float4*)(xls + (rg + 8 * rr) * D_ + i);
                accv[rr] += xv.x * r0;
                accv[rr] += xv.y * r1;
                accv[rr] += xv.z * r2;
                accv[rr] += xv.w * r3;
            }
        }
        #pragma unroll
        for (int rr = 0; rr < 4; ++rr) {
            int tt = tbase + rg + 8 * rr;
            A2[(size_t)(tt * 8 + b) * KA + 1024 + kk] = f2bf(accv[rr]);
            size_t base = (size_t)(b * K_ + kk) * T_;
            if (tt < T_ - 1) xpT[base + tt + 1] = accv[rr];
            if (tt == 0)     xpT[base] = 0.f;
        }
    }
}

// ---------------------------------------------------------------------------
// K_SCAN: verified round-0/3/8 version, unchanged.
// ---------------------------------------------------------------------------
__global__ __launch_bounds__(512) void k_scan(const float* __restrict__ xpT,
                                              const float* __restrict__ ws,
                                              uint_t* __restrict__ A2u) {
    __shared__ float xls[T_];          // 8 KB
    __shared__ float Er[512], Ei[512]; // 4 KB  (E, then seeds, [c*16+j])

    int tid = threadIdx.x;
    int k = blockIdx.x & 31, b = blockIdx.x >> 5;
    int c = tid >> 4, j = tid & 15;
    int col = k * 16 + j;

    // 1) stage series
    ((float4*)xls)[tid] = ((const float4*)(xpT + (size_t)(b * K_ + k) * T_))[tid];
    __syncthreads();

    float lr = ws[col], li = ws[512 + col];
    float br = ws[1024 + col], bi = ws[1536 + col];

    // 2) pass-1: chunk end-state
    {
        float sr = 0.f, si = 0.f;
        const float* xc = xls + c * CL;
        #pragma unroll 4
        for (int p = 0; p < CL; ++p) {
            float x1 = xc[p];
            float nr = br * x1 + lr * sr - li * si;
            float ni = bi * x1 + lr * si + li * sr;
            sr = nr; si = ni;
        }
        Er[c * 16 + j] = sr;
        Ei[c * 16 + j] = si;
    }
    __syncthreads();

    // 3) carry combine (16 threads), in-place: E[c] becomes the SEED of chunk c
    if (tid < 16) {
        float pr = lr, pi = li;            // lambda^64 via 6 squarings
        #pragma unroll
        for (int q = 0; q < 6; ++q) {
            float nr = pr * pr - pi * pi;
            float ni = 2.f * pr * pi;
            pr = nr; pi = ni;
        }
        float sr = 0.f, si = 0.f;
        for (int cc = 0; cc < CHK; ++cc) {
            int idx = cc * 16 + tid;
            float er = Er[idx], ei = Ei[idx];
            Er[idx] = sr; Ei[idx] = si;
            float nr = pr * sr - pi * si + er;
            float ni = pr * si + pi * sr + ei;
            sr = nr; si = ni;
        }
    }
    __syncthreads();

    // 4) pass-2: seeded scan, write A2
    {
        float sr = Er[c * 16 + j], si = Ei[c * 16 + j];
        int t0 = c * CL;
        const float* xc = xls + t0;
        uint_t* Ab = A2u + (size_t)(t0 * 8 + b) * (KA / 2) + col;
        #pragma unroll 4
        for (int p = 0; p < CL; ++p) {
            float x1 = xc[p];
            float nr = br * x1 + lr * sr - li * si;
            float ni = bi * x1 + lr * si + li * sr;
            sr = nr; si = ni;
            Ab[0] = pack_bf2(sr, si);
            Ab += 8 * (KA / 2);
        }
    }
}

// ---------------------------------------------------------------------------
// K_GEMM2: verified round-8 version, unchanged (16B-vectorized stage).
// ---------------------------------------------------------------------------
__global__ __launch_bounds__(512) void k_gemm2(const uint_t* __restrict__ A2u,
                                               const ushort_t* __restrict__ Wt,
                                               const float* __restrict__ Do,
                                               float* __restrict__ out) {
    __shared__ __align__(16) char smem[32 * ABYTES];   // 69632 B

    int tid = threadIdx.x;
    int bid = blockIdx.x;

    // stage: 4224 x 16B chunks = 32 rows x 132 chunks, flat, coalesced
    const uint4* src4 = (const uint4*)(A2u + (size_t)bid * (32 * (KA / 2)));
    #pragma unroll
    for (int it = 0; it < 9; ++it) {
        int f = it * 512 + tid;
        if (f < 4224) {
            uint4 v = src4[f];
            int row = f / 132;
            int c16 = f - row * 132;
            int bo = (row * ABYTES + c16 * 16) ^ ((row & 7) << 4);
            *(uint4*)(smem + bo) = v;
        }
    }
    __syncthreads();

    int wave = tid >> 6, lane = tid & 63;
    int l16 = lane & 15, quad = lane >> 4;
    int rh = wave & 1, cf = wave >> 1;
    int arow = rh * 16 + l16;
    int abase = arow * ABYTES + quad * 16;
    int aswz = (arow & 7) << 4;
    const ushort_t* Wp0 = Wt + (size_t)(cf * 32 + l16) * KA + quad * 8;
    const ushort_t* Wp1 = Wp0 + (size_t)16 * KA;

    floatx4 acc0 = {0.f, 0.f, 0.f, 0.f}, acc1 = {0.f, 0.f, 0.f, 0.f};
    for (int ks = 0; ks < 33; ++ks) {
        short8 av = *(const short8*)(smem + ((abase + ks * 64) ^ aswz));
        short8 b0 = *(const short8*)(Wp0 + ks * 32);
        short8 b1 = *(const short8*)(Wp1 + ks * 32);
        acc0 = __builtin_amdgcn_mfma_f32_16x16x32_bf16(av, b0, acc0, 0, 0, 0);
        acc1 = __builtin_amdgcn_mfma_f32_16x16x32_bf16(av, b1, acc1, 0, 0, 0);
    }

    int col0 = cf * 32 + l16;
    float dv0 = Do[col0], dv1 = Do[col0 + 16];
    #pragma unroll
    for (int q = 0; q < 4; ++q) {
        int r = bid * 32 + rh * 16 + quad * 4 + q;
        int b = r & 7, t = r >> 3;
        float* op = out + (size_t)(b * T_ + t) * M_;
        op[col0]      = acc0[q] + dv0;
        op[col0 + 16] = acc1[q] + dv1;
    }
}

// ---------------------------------------------------------------------------
extern "C" void kernel_launch(void* const* d_in, const int* in_sizes, int n_in,
                              void* d_out, int out_size, void* d_ws, size_t ws_size,
                              hipStream_t stream) {
    const float* x     = (const float*)d_in[0];
    const float* R     = (const float*)d_in[1];
    const float* theta = (const float*)d_in[2];
    const float* lnC_r = (const float*)d_in[3];
    const float* lnC_i = (const float*)d_in[4];
    const float* D     = (const float*)d_in[5];
    const float* Do    = (const float*)d_in[6];
    float* out = (float*)d_out;

    float* wsf   = (float*)d_ws;
    float* lambp = wsf;                               // 2048 floats
    ushort_t* Wt = (ushort_t*)(wsf + 2048);           // 135168 ushorts = 67584 floats
    ushort_t* A2 = (ushort_t*)(wsf + 2048 + 67584);   // BT*KA ushorts = 8650752 floats
    float* xpT   = wsf + 2048 + 67584 + 8650752;      // 524288 floats

    k_pre<<<785, 256, 0, stream>>>(theta, lnC_r, lnC_i, D, x, R,
                                   lambp, Wt, xpT, A2);
    k_scan<<<256, 512, 0, stream>>>(xpT, lambp, (uint_t*)A2);
    k_gemm2<<<512, 512, 0, stream>>>((const uint_t*)A2, Wt, Do, out);
}